// Round 1
// baseline (3616.539 us; speedup 1.0000x reference)
//
#include <hip/hip_runtime.h>
#include <math.h>

#define N_NODES 100000
#define N_EDGES 1600000
#define HID 128
#define OUTD 47

#define NPB 128                       // nodes per fine bucket
#define NB 782                        // ceil(100000/128)
#define BCAP 2560                     // record capacity per fine bucket (mean 2046, max ~2300)
#define CHUNK 2048                    // edges per phase-A block
#define NCHB 782                      // phase-A binning blocks
#define CWB 64                        // convw blocks appended to binA grid

typedef short bf16x8 __attribute__((ext_vector_type(8)));
typedef float f32x4 __attribute__((ext_vector_type(4)));

__device__ inline unsigned short f2bf(float x) {
    union { float f; unsigned int u; } v; v.f = x;
    unsigned int r = v.u + 0x7fffu + ((v.u >> 16) & 1u);   // RNE
    return (unsigned short)(r >> 16);
}
__device__ inline float bf_lo(unsigned int u) { return __uint_as_float(u << 16); }
__device__ inline float bf_hi(unsigned int u) { return __uint_as_float(u & 0xffff0000u); }

// src-chunk for gather locality: 16 chunks of 6250 nodes
__device__ inline unsigned int src_chunk(unsigned int s) {
    return (s * 42950u) >> 28;   // == s / 6250 for s < 100000
}

// ---------------- Phase A: bin edges by dst fine-bucket + (appended blocks) weight convert ----------------

__global__ __launch_bounds__(256) void binA_k(
    const int* __restrict__ src, const int* __restrict__ dst,
    int* __restrict__ gcur, unsigned int* __restrict__ binned,
    const float* __restrict__ W0, const float* __restrict__ W1, const float* __restrict__ W2,
    unsigned short* __restrict__ Wt0, unsigned short* __restrict__ Wt1,
    unsigned short* __restrict__ Wt2)
{
    __shared__ unsigned int sortedL[CHUNK];       // 8 KB
    __shared__ unsigned short bucketOf[CHUNK];    // 4 KB
    __shared__ int cntL[NB];
    __shared__ int excL[NB];
    __shared__ int curL[NB];
    __shared__ int gposL[NB];
    __shared__ int partial[256];

    int t = threadIdx.x;

    if (blockIdx.x >= NCHB) {
        // weight-convert tail blocks
        int i = (blockIdx.x - NCHB) * 256 + t;
        if (i < 16384) {
            int n = i >> 7, k = i & 127;
            Wt0[i] = f2bf(W0[k * 128 + n]);
            Wt1[i] = f2bf(W1[k * 128 + n]);
        }
        if (i < 64 * 128) {               // Wt2 padded to 64 output cols (zeros past 47)
            int n = i >> 7, k = i & 127;
            Wt2[i] = (n < OUTD) ? f2bf(W2[k * OUTD + n]) : (unsigned short)0;
        }
        return;
    }

    int e0 = blockIdx.x * CHUNK;

    for (int i = t; i < NB; i += 256) cntL[i] = 0;
    __syncthreads();

    for (int i = t; i < CHUNK; i += 256) {
        int e = e0 + i;
        if (e < N_EDGES) atomicAdd(&cntL[dst[e] >> 7], 1);
    }
    __syncthreads();

    // exclusive scan of cntL[NB]
    int b4 = t * 4;
    int c0 = (b4 + 0 < NB) ? cntL[b4 + 0] : 0;
    int c1 = (b4 + 1 < NB) ? cntL[b4 + 1] : 0;
    int c2 = (b4 + 2 < NB) ? cntL[b4 + 2] : 0;
    int c3 = (b4 + 3 < NB) ? cntL[b4 + 3] : 0;
    int lsum = c0 + c1 + c2 + c3;
    partial[t] = lsum;
    __syncthreads();
    for (int off = 1; off < 256; off <<= 1) {
        int x = (t >= off) ? partial[t - off] : 0;
        __syncthreads();
        partial[t] += x;
        __syncthreads();
    }
    int pbase = partial[t] - lsum;
    if (b4 + 0 < NB) { excL[b4 + 0] = pbase;                curL[b4 + 0] = pbase; }
    if (b4 + 1 < NB) { excL[b4 + 1] = pbase + c0;           curL[b4 + 1] = pbase + c0; }
    if (b4 + 2 < NB) { excL[b4 + 2] = pbase + c0 + c1;      curL[b4 + 2] = pbase + c0 + c1; }
    if (b4 + 3 < NB) { excL[b4 + 3] = pbase + c0 + c1 + c2; curL[b4 + 3] = pbase + c0 + c1 + c2; }
    __syncthreads();

    int tot = partial[255];

    for (int i = t; i < CHUNK; i += 256) {
        int e = e0 + i;
        if (e < N_EDGES) {
            int d = dst[e];
            int s = src[e];
            int bkt = d >> 7;
            int pos = atomicAdd(&curL[bkt], 1);
            sortedL[pos] = ((unsigned int)s << 7) | (unsigned int)(d & 127);
            bucketOf[pos] = (unsigned short)bkt;
        }
    }
    __syncthreads();

    for (int b = t; b < NB; b += 256) {
        int c = cntL[b];
        gposL[b] = c ? atomicAdd(&gcur[b], c) : 0;
    }
    __syncthreads();

    for (int i = t; i < tot; i += 256) {
        unsigned int r = sortedL[i];
        int bkt = bucketOf[i];
        binned[(size_t)bkt * BCAP + gposL[bkt] + (i - excL[bkt])] = r;
    }
}

// ---------------- Phase B: per-fine-bucket chunk-major sort (in place) + dinv ----------------
// key = (src_chunk << 7) | localnode  -> all waves of aggf co-traverse src chunks in order.

__global__ __launch_bounds__(256) void binB_k(
    unsigned int* __restrict__ binned, const int* __restrict__ gcur,
    float* __restrict__ dinv)
{
    __shared__ unsigned int recL[BCAP];   // 10 KB
    __shared__ unsigned int colL[BCAP];   // 10 KB
    __shared__ int hist[2048];            // 8 KB
    __shared__ int partial[256];

    int b = blockIdx.x, t = threadIdx.x;
    int cnt = gcur[b];
    unsigned int* rp = binned + (size_t)b * BCAP;

    for (int i = t; i < 2048; i += 256) hist[i] = 0;
    __syncthreads();

    for (int i = t; i < cnt; i += 256) {
        unsigned int r = rp[i];
        recL[i] = r;
        unsigned int key = (src_chunk(r >> 7) << 7) | (r & 127u);
        atomicAdd(&hist[key], 1);
    }
    __syncthreads();

    // degree -> dinv (before scan overwrites hist)
    if (t < NPB) {
        int node = b * NPB + t;
        if (node < N_NODES) {
            int deg = 0;
#pragma unroll
            for (int c = 0; c < 16; c++) deg += hist[(c << 7) | t];
            dinv[node] = rsqrtf((float)(deg + 1));   // +1 self-loop
        }
    }

    // in-place exclusive scan of hist[2048]
    int base8 = t * 8;
    int v[8], lsum = 0;
#pragma unroll
    for (int j = 0; j < 8; j++) { v[j] = hist[base8 + j]; lsum += v[j]; }
    partial[t] = lsum;
    __syncthreads();
    for (int off = 1; off < 256; off <<= 1) {
        int x = (t >= off) ? partial[t - off] : 0;
        __syncthreads();
        partial[t] += x;
        __syncthreads();
    }
    int run = partial[t] - lsum;
#pragma unroll
    for (int j = 0; j < 8; j++) { hist[base8 + j] = run; run += v[j]; }
    __syncthreads();

    for (int i = t; i < cnt; i += 256) {
        unsigned int r = recL[i];
        unsigned int key = (src_chunk(r >> 7) << 7) | (r & 127u);
        int pos = atomicAdd(&hist[key], 1);
        colL[pos] = r;                         // keep full packed record
    }
    __syncthreads();
    for (int i = t; i < cnt; i += 256) rp[i] = colL[i];   // write back in place
}

// ---------------- MFMA GEMM (M x 128 @ 128 x N), fused BN-final+BN-apply+ReLU, dinv prescale ----------------

template <int ABF16, int MODE, int NT, int OBF16>
__global__ __launch_bounds__(256) void gemm_k(
    const void* __restrict__ Ap, const unsigned short* __restrict__ Wt,
    const float* __restrict__ bnSum, const float* __restrict__ bnSq,
    const float* __restrict__ gam, const float* __restrict__ bet,
    const float* __restrict__ dinv, void* __restrict__ Outp,
    int ncols, int ostride)
{
    __shared__ unsigned short WtL[NT * 16][136];
    __shared__ float sS[128], sT[128];

    int t = threadIdx.x;
    if (MODE) {
        if (t < 128) {
            float mean = bnSum[t] * (1.0f / N_NODES);
            float var = bnSq[t] * (1.0f / N_NODES) - mean * mean;
            float inv = rsqrtf(var + 1e-5f);
            float s = gam[t] * inv;
            sS[t] = s;
            sT[t] = bet[t] - mean * s;
        }
    }

    const int TOT = NT * 16 * 128;
    for (int e = t * 8; e < TOT; e += 256 * 8) {
        int n = e >> 7, k = e & 127;
        uint4 v = *(const uint4*)(Wt + e);
        *(uint4*)&WtL[n][k] = v;
    }
    __syncthreads();

    int wave = t >> 6, lane = t & 63;
    int quad = lane >> 4, m16 = lane & 15;
    int rbase = blockIdx.x * 128 + wave * 32;

    f32x4 acc[2][NT];
#pragma unroll
    for (int rt = 0; rt < 2; rt++)
#pragma unroll
        for (int ct = 0; ct < NT; ct++) acc[rt][ct] = (f32x4){0.f, 0.f, 0.f, 0.f};

#pragma unroll
    for (int kc = 0; kc < 4; kc++) {
        int kb = kc * 32 + quad * 8;
        bf16x8 afrag[2];
#pragma unroll
        for (int rt = 0; rt < 2; rt++) {
            int row = rbase + rt * 16 + m16;
            bool rv = (row < N_NODES);
            if (ABF16) {
                uint4 v = make_uint4(0, 0, 0, 0);
                if (rv) v = *(const uint4*)((const unsigned short*)Ap + (size_t)row * 128 + kb);
                if (MODE) {
                    unsigned int uu[4] = {v.x, v.y, v.z, v.w};
                    unsigned short* fp = (unsigned short*)&afrag[rt];
#pragma unroll
                    for (int i = 0; i < 4; i++) {
                        int k0 = kb + 2 * i;
                        float lo = fmaxf(bf_lo(uu[i]) * sS[k0] + sT[k0], 0.f);
                        float hi = fmaxf(bf_hi(uu[i]) * sS[k0 + 1] + sT[k0 + 1], 0.f);
                        fp[2 * i] = f2bf(lo);
                        fp[2 * i + 1] = f2bf(hi);
                    }
                } else {
                    afrag[rt] = *(bf16x8*)&v;
                }
            } else {
                const float* ap = (const float*)Ap + (size_t)row * 128 + kb;
                float4 f0 = make_float4(0.f, 0.f, 0.f, 0.f), f1 = f0;
                if (rv) { f0 = *(const float4*)ap; f1 = *(const float4*)(ap + 4); }
                unsigned short* fp = (unsigned short*)&afrag[rt];
                fp[0] = f2bf(f0.x); fp[1] = f2bf(f0.y); fp[2] = f2bf(f0.z); fp[3] = f2bf(f0.w);
                fp[4] = f2bf(f1.x); fp[5] = f2bf(f1.y); fp[6] = f2bf(f1.z); fp[7] = f2bf(f1.w);
            }
        }
#pragma unroll
        for (int ct = 0; ct < NT; ct++) {
            bf16x8 bfrag = *(bf16x8*)&WtL[ct * 16 + m16][kb];
#pragma unroll
            for (int rt = 0; rt < 2; rt++)
                acc[rt][ct] = __builtin_amdgcn_mfma_f32_16x16x32_bf16(
                    afrag[rt], bfrag, acc[rt][ct], 0, 0, 0);
        }
    }

#pragma unroll
    for (int rt = 0; rt < 2; rt++)
#pragma unroll
        for (int r = 0; r < 4; r++) {
            int row = rbase + rt * 16 + quad * 4 + r;
            if (row < N_NODES) {
                float d = dinv[row];
#pragma unroll
                for (int ct = 0; ct < NT; ct++) {
                    int c = ct * 16 + m16;
                    if (c < ncols) {
                        float val = acc[rt][ct][r] * d;
                        if (OBF16)
                            ((unsigned short*)Outp)[(size_t)row * ostride + c] = f2bf(val);
                        else
                            ((float*)Outp)[(size_t)row * ostride + c] = val;
                    }
                }
            }
        }
}

// ---------------- Fused aggregation: record-major LDS-atomic scatter ----------------
// Block = one fine bucket (128 dst nodes). acc split even/odd channel halves so each
// ds_add_f32 is a free 2-way bank pattern. Epilogue fuses self-loop + bias + dinv
// scale + bf16 store + BN sum/sq statistics (bnstats_k eliminated).

__global__ __launch_bounds__(1024, 8) void aggf_k(
    const unsigned int* __restrict__ H,      // bf16 rows [N][128] as 64 uints
    const unsigned int* __restrict__ recs,   // packed (src<<7|dstlocal), chunk-major
    const int* __restrict__ gcur,
    const float* __restrict__ dinv,
    const float* __restrict__ bias,
    float* __restrict__ bnSum, float* __restrict__ bnSq,
    unsigned int* __restrict__ out)          // bf16 rows [N][128]
{
    __shared__ float acc[16384];             // 64 KB: [0..8191]=even ch, [8192..]=odd ch
    int t = threadIdx.x, b = blockIdx.x;
    int lane = t & 63, w = t >> 6;           // 16 waves

    for (int i = t; i < 16384; i += 1024) acc[i] = 0.f;
    __syncthreads();

    int cnt = gcur[b];
    const unsigned int* rp = recs + (size_t)b * BCAP;

    for (int i0 = w * 64; i0 < cnt; i0 += 1024) {
        int m = min(64, cnt - i0);
        unsigned int rv = 0;
        if (lane < m) rv = rp[i0 + lane];
        int j = 0;
        for (; j + 4 <= m; j += 4) {         // 4 independent gathers in flight
            unsigned int r0 = __shfl(rv, j);
            unsigned int r1 = __shfl(rv, j + 1);
            unsigned int r2 = __shfl(rv, j + 2);
            unsigned int r3 = __shfl(rv, j + 3);
            unsigned int u0 = H[(r0 >> 7) * 64 + lane];
            unsigned int u1 = H[(r1 >> 7) * 64 + lane];
            unsigned int u2 = H[(r2 >> 7) * 64 + lane];
            unsigned int u3 = H[(r3 >> 7) * 64 + lane];
            int e0 = (int)((r0 & 127u) << 6) + lane;
            int e1 = (int)((r1 & 127u) << 6) + lane;
            int e2 = (int)((r2 & 127u) << 6) + lane;
            int e3 = (int)((r3 & 127u) << 6) + lane;
            atomicAdd(&acc[e0], bf_lo(u0)); atomicAdd(&acc[e0 + 8192], bf_hi(u0));
            atomicAdd(&acc[e1], bf_lo(u1)); atomicAdd(&acc[e1 + 8192], bf_hi(u1));
            atomicAdd(&acc[e2], bf_lo(u2)); atomicAdd(&acc[e2 + 8192], bf_hi(u2));
            atomicAdd(&acc[e3], bf_lo(u3)); atomicAdd(&acc[e3 + 8192], bf_hi(u3));
        }
        for (; j < m; j++) {
            unsigned int r = __shfl(rv, j);
            unsigned int u = H[(r >> 7) * 64 + lane];
            int e = (int)((r & 127u) << 6) + lane;
            atomicAdd(&acc[e], bf_lo(u)); atomicAdd(&acc[e + 8192], bf_hi(u));
        }
    }
    __syncthreads();

    // epilogue: 16 waves x 8 nodes each; lane owns channels 2*lane, 2*lane+1
    float b_lo = bias[2 * lane], b_hi = bias[2 * lane + 1];
    float s0 = 0.f, s1 = 0.f, q0 = 0.f, q1 = 0.f;
    int n0 = b * NPB + w * 8;
#pragma unroll
    for (int k = 0; k < 8; k++) {
        int node = n0 + k;
        if (node < N_NODES) {
            int d = w * 8 + k;
            float dv = dinv[node];
            unsigned int su = H[(size_t)node * 64 + lane];   // self-loop (prescaled)
            float vx = (acc[d * 64 + lane] + bf_lo(su)) * dv + b_lo;
            float vy = (acc[d * 64 + lane + 8192] + bf_hi(su)) * dv + b_hi;
            out[(size_t)node * 64 + lane] =
                (unsigned int)f2bf(vx) | ((unsigned int)f2bf(vy) << 16);
            s0 += vx; q0 += vx * vx;
            s1 += vy; q1 += vy * vy;
        }
    }

    // BN stats: cross-wave reduce in (now-free) acc, 256 global atomics per block
    __syncthreads();
    acc[        w * 64 + lane] = s0;
    acc[1024 +  w * 64 + lane] = s1;
    acc[2048 +  w * 64 + lane] = q0;
    acc[3072 +  w * 64 + lane] = q1;
    __syncthreads();
    if (t < 256) {
        int qty = t >> 6, l = t & 63;
        float tot = 0.f;
#pragma unroll
        for (int ww = 0; ww < 16; ww++) tot += acc[qty * 1024 + ww * 64 + l];
        int ch = 2 * l + (qty & 1);
        float* dstp = (qty < 2) ? bnSum : bnSq;
        atomicAdd(&dstp[ch], tot);
    }
}

// ---------------- Final fused aggregation + log_softmax (Hf padded to 64 ch) ----------------

__global__ __launch_bounds__(512, 8) void aggo_k(
    const unsigned int* __restrict__ Hf,     // bf16 rows [N][64] as 32 uints
    const unsigned int* __restrict__ recs,
    const int* __restrict__ gcur,
    const float* __restrict__ dinv,
    const float* __restrict__ b2,
    float* __restrict__ out)
{
    __shared__ float acc[8192];              // 32 KB: [0..4095]=even ch, [4096..]=odd ch
    int t = threadIdx.x, b = blockIdx.x;
    int lane = t & 63, w = t >> 6;           // 8 waves
    int half = lane >> 5, c = lane & 31;     // half-wave per record, 2 records/instr

    for (int i = t; i < 8192; i += 512) acc[i] = 0.f;
    __syncthreads();

    int cnt = gcur[b];
    const unsigned int* rp = recs + (size_t)b * BCAP;

    for (int i0 = w * 64; i0 < cnt; i0 += 512) {
        int m = min(64, cnt - i0);
        unsigned int rv = 0;
        if (lane < m) rv = rp[i0 + lane];
        int j = 0;
        for (; j + 4 <= m; j += 4) {
            unsigned int ra = __shfl(rv, j + half);
            unsigned int rb = __shfl(rv, j + 2 + half);
            unsigned int ua = Hf[(ra >> 7) * 32 + c];
            unsigned int ub = Hf[(rb >> 7) * 32 + c];
            int ea = (int)((ra & 127u) << 5) + c;
            int eb = (int)((rb & 127u) << 5) + c;
            atomicAdd(&acc[ea], bf_lo(ua)); atomicAdd(&acc[ea + 4096], bf_hi(ua));
            atomicAdd(&acc[eb], bf_lo(ub)); atomicAdd(&acc[eb + 4096], bf_hi(ub));
        }
        for (; j + 2 <= m; j += 2) {
            unsigned int ra = __shfl(rv, j + half);
            unsigned int ua = Hf[(ra >> 7) * 32 + c];
            int ea = (int)((ra & 127u) << 5) + c;
            atomicAdd(&acc[ea], bf_lo(ua)); atomicAdd(&acc[ea + 4096], bf_hi(ua));
        }
        if (j < m) {
            unsigned int ra = __shfl(rv, j);
            if (half == 0) {
                unsigned int ua = Hf[(ra >> 7) * 32 + c];
                int ea = (int)((ra & 127u) << 5) + c;
                atomicAdd(&acc[ea], bf_lo(ua)); atomicAdd(&acc[ea + 4096], bf_hi(ua));
            }
        }
    }
    __syncthreads();

    // epilogue: 4 threads per node, 12 channels each; log_softmax over 47
    int d = t >> 2, sub = t & 3;
    int node = b * NPB + d;
    if (node < N_NODES) {
        float dv = dinv[node];
        float v[12];
        float mx = -INFINITY;
#pragma unroll
        for (int k = 0; k < 12; k++) {
            int ch = sub * 12 + k;
            float val = -INFINITY;
            if (ch < OUTD) {
                int cc = ch >> 1;
                float a = (ch & 1) ? acc[d * 32 + cc + 4096] : acc[d * 32 + cc];
                unsigned int su = Hf[(size_t)node * 32 + cc];
                float sv = (ch & 1) ? bf_hi(su) : bf_lo(su);
                val = (a + sv) * dv + b2[ch];
            }
            v[k] = val;
            mx = fmaxf(mx, val);
        }
        mx = fmaxf(mx, __shfl_xor(mx, 1));
        mx = fmaxf(mx, __shfl_xor(mx, 2));
        float es = 0.f;
#pragma unroll
        for (int k = 0; k < 12; k++) {
            if (sub * 12 + k < OUTD) es += __expf(v[k] - mx);
        }
        es += __shfl_xor(es, 1);
        es += __shfl_xor(es, 2);
        float ls = logf(es);
        float* op = out + (size_t)node * OUTD + sub * 12;
#pragma unroll
        for (int k = 0; k < 12; k++) {
            if (sub * 12 + k < OUTD) op[k] = v[k] - mx - ls;
        }
    }
}

// ---------------- launch ----------------

extern "C" void kernel_launch(void* const* d_in, const int* in_sizes, int n_in,
                              void* d_out, int out_size, void* d_ws, size_t ws_size,
                              hipStream_t stream)
{
    const float* x   = (const float*)d_in[0];
    const int*   ei  = (const int*)d_in[1];
    const float* W0  = (const float*)d_in[2];
    const float* b0  = (const float*)d_in[3];
    const float* W1  = (const float*)d_in[4];
    const float* b1  = (const float*)d_in[5];
    const float* W2  = (const float*)d_in[6];
    const float* b2  = (const float*)d_in[7];
    const float* g0  = (const float*)d_in[8];
    const float* be0 = (const float*)d_in[9];
    const float* g1  = (const float*)d_in[10];
    const float* be1 = (const float*)d_in[11];
    const int* srcv = ei;
    const int* dstv = ei + N_EDGES;

    char* w = (char*)d_ws;
    unsigned int* H0 = (unsigned int*)w;  w += (size_t)N_NODES * 128 * 2;   // bf16 [N][128]
    unsigned int* H1 = (unsigned int*)w;  w += (size_t)N_NODES * 128 * 2;   // bf16 [N][128]
    unsigned int* Hf = (unsigned int*)w;  w += (size_t)N_NODES * 64 * 2;    // bf16 [N][64]
    unsigned int* binned = (unsigned int*)w; w += (size_t)NB * BCAP * 4;    // 8.0 MB (doubles as record list)
    unsigned short* Wt0 = (unsigned short*)w; w += 16384 * 2;
    unsigned short* Wt1 = (unsigned short*)w; w += 16384 * 2;
    unsigned short* Wt2 = (unsigned short*)w; w += 64 * 128 * 2;
    float* dinv = (float*)w;    w += (size_t)N_NODES * 4;
    // single-memset region: gcur (784 ints) + bnS0,bnQ0,bnS1,bnQ1 (512 floats)
    int* gcur = (int*)w;        w += 784 * 4;
    float* bnS0 = (float*)w;    w += 128 * 4;
    float* bnQ0 = (float*)w;    w += 128 * 4;
    float* bnS1 = (float*)w;    w += 128 * 4;
    float* bnQ1 = (float*)w;    w += 128 * 4;

    int gb = (N_NODES + 127) / 128;       // 782

    hipMemsetAsync(gcur, 0, (784 + 512) * 4, stream);

    binA_k<<<NCHB + CWB, 256, 0, stream>>>(srcv, dstv, gcur, binned,
                                           W0, W1, W2, Wt0, Wt1, Wt2);
    binB_k<<<NB, 256, 0, stream>>>(binned, gcur, dinv);

    // Layer 0: x fp32 -> H0 bf16 (dinv-prescaled); agg fuses bias + BN stats
    gemm_k<0, 0, 8, 1><<<gb, 256, 0, stream>>>(x, Wt0, nullptr, nullptr, nullptr, nullptr,
                                               dinv, H0, 128, 128);
    aggf_k<<<NB, 1024, 0, stream>>>(H0, binned, gcur, dinv, b0, bnS0, bnQ0, H1);

    // Layer 1: BN-final+BN-apply+ReLU fused into gemm, bf16 MFMA
    gemm_k<1, 1, 8, 1><<<gb, 256, 0, stream>>>(H1, Wt1, bnS0, bnQ0, g0, be0,
                                               dinv, H0, 128, 128);
    aggf_k<<<NB, 1024, 0, stream>>>(H0, binned, gcur, dinv, b1, bnS1, bnQ1, H1);

    // Layer 2: 64-wide padded out (bf16) + fused log_softmax aggregation
    gemm_k<1, 1, 4, 1><<<gb, 256, 0, stream>>>(H1, Wt2, bnS1, bnQ1, g1, be1,
                                               dinv, Hf, 64, 64);
    aggo_k<<<NB, 512, 0, stream>>>(Hf, binned, gcur, dinv, b2, (float*)d_out);
}

// Round 2
// 453.342 us; speedup vs baseline: 7.9775x; 7.9775x over previous
//
#include <hip/hip_runtime.h>
#include <math.h>

#define N_NODES 100000
#define N_EDGES 1600000
#define HID 128
#define OUTD 47
#define OSTR 48

#define NPB 128                       // nodes per fine bucket
#define NB 782                        // ceil(100000/128)
#define BCAP 2560                     // record capacity per fine bucket (mean 2046, max ~2300)
#define CHUNK 2048                    // edges per phase-A block
#define NCHB 782                      // phase-A binning blocks
#define CWB 64                        // convw blocks appended to binA grid
#define NAB 1563                      // agg4 blocks: ceil(100000/64)

typedef short bf16x8 __attribute__((ext_vector_type(8)));
typedef float f32x4 __attribute__((ext_vector_type(4)));

__device__ inline unsigned short f2bf(float x) {
    union { float f; unsigned int u; } v; v.f = x;
    unsigned int r = v.u + 0x7fffu + ((v.u >> 16) & 1u);   // RNE
    return (unsigned short)(r >> 16);
}
__device__ inline float bf_lo(unsigned int u) { return __uint_as_float(u << 16); }
__device__ inline float bf_hi(unsigned int u) { return __uint_as_float(u & 0xffff0000u); }

// src-chunk for gather locality: 16 chunks of 6250 nodes
__device__ inline unsigned int src_chunk(unsigned int s) {
    return (s * 42950u) >> 28;   // == s / 6250 for s < 100000
}

// ---------------- Phase A: bin edges by dst fine-bucket + (appended blocks) weight convert ----------------

__global__ __launch_bounds__(256) void binA_k(
    const int* __restrict__ src, const int* __restrict__ dst,
    int* __restrict__ gcur, unsigned int* __restrict__ binned,
    const float* __restrict__ W0, const float* __restrict__ W1, const float* __restrict__ W2,
    unsigned short* __restrict__ Wt0, unsigned short* __restrict__ Wt1,
    unsigned short* __restrict__ Wt2)
{
    __shared__ unsigned int sortedL[CHUNK];       // 8 KB
    __shared__ unsigned short bucketOf[CHUNK];    // 4 KB
    __shared__ int cntL[NB];
    __shared__ int excL[NB];
    __shared__ int curL[NB];
    __shared__ int gposL[NB];
    __shared__ int partial[256];

    int t = threadIdx.x;

    if (blockIdx.x >= NCHB) {
        // weight-convert tail blocks
        int i = (blockIdx.x - NCHB) * 256 + t;
        if (i < 16384) {
            int n = i >> 7, k = i & 127;
            Wt0[i] = f2bf(W0[k * 128 + n]);
            Wt1[i] = f2bf(W1[k * 128 + n]);
        }
        if (i < 48 * 128) {
            int n = i >> 7, k = i & 127;
            Wt2[i] = (n < OUTD) ? f2bf(W2[k * OUTD + n]) : (unsigned short)0;
        }
        return;
    }

    int e0 = blockIdx.x * CHUNK;

    for (int i = t; i < NB; i += 256) cntL[i] = 0;
    __syncthreads();

    for (int i = t; i < CHUNK; i += 256) {
        int e = e0 + i;
        if (e < N_EDGES) atomicAdd(&cntL[dst[e] >> 7], 1);
    }
    __syncthreads();

    // exclusive scan of cntL[NB]
    int b4 = t * 4;
    int c0 = (b4 + 0 < NB) ? cntL[b4 + 0] : 0;
    int c1 = (b4 + 1 < NB) ? cntL[b4 + 1] : 0;
    int c2 = (b4 + 2 < NB) ? cntL[b4 + 2] : 0;
    int c3 = (b4 + 3 < NB) ? cntL[b4 + 3] : 0;
    int lsum = c0 + c1 + c2 + c3;
    partial[t] = lsum;
    __syncthreads();
    for (int off = 1; off < 256; off <<= 1) {
        int x = (t >= off) ? partial[t - off] : 0;
        __syncthreads();
        partial[t] += x;
        __syncthreads();
    }
    int pbase = partial[t] - lsum;
    if (b4 + 0 < NB) { excL[b4 + 0] = pbase;                curL[b4 + 0] = pbase; }
    if (b4 + 1 < NB) { excL[b4 + 1] = pbase + c0;           curL[b4 + 1] = pbase + c0; }
    if (b4 + 2 < NB) { excL[b4 + 2] = pbase + c0 + c1;      curL[b4 + 2] = pbase + c0 + c1; }
    if (b4 + 3 < NB) { excL[b4 + 3] = pbase + c0 + c1 + c2; curL[b4 + 3] = pbase + c0 + c1 + c2; }
    __syncthreads();

    int tot = partial[255];

    for (int i = t; i < CHUNK; i += 256) {
        int e = e0 + i;
        if (e < N_EDGES) {
            int d = dst[e];
            int s = src[e];
            int bkt = d >> 7;
            int pos = atomicAdd(&curL[bkt], 1);
            sortedL[pos] = ((unsigned int)s << 7) | (unsigned int)(d & 127);
            bucketOf[pos] = (unsigned short)bkt;
        }
    }
    __syncthreads();

    for (int b = t; b < NB; b += 256) {
        int c = cntL[b];
        gposL[b] = c ? atomicAdd(&gcur[b], c) : 0;
    }
    __syncthreads();

    for (int i = t; i < tot; i += 256) {
        unsigned int r = sortedL[i];
        int bkt = bucketOf[i];
        binned[(size_t)bkt * BCAP + gposL[bkt] + (i - excL[bkt])] = r;
    }
}

// ---------------- Phase B: per-fine-bucket CSR finalize into fixed regions ----------------

__global__ __launch_bounds__(256) void binB_k(
    const unsigned int* __restrict__ binned, const int* __restrict__ gcur,
    int2* __restrict__ rowse, float* __restrict__ dinv, int* __restrict__ colv)
{
    __shared__ unsigned int recL[BCAP];   // 10 KB
    __shared__ int colL[BCAP];            // 10 KB
    __shared__ int hist[2048];            // 8 KB: key = (localnode<<4) | src_chunk
    __shared__ int partial[256];

    int b = blockIdx.x, t = threadIdx.x;
    int cnt = gcur[b];
    int base = b * BCAP;
    const unsigned int* rp = binned + (size_t)b * BCAP;

    for (int i = t; i < 2048; i += 256) hist[i] = 0;
    __syncthreads();

    for (int i = t; i < cnt; i += 256) {
        unsigned int r = rp[i];
        recL[i] = r;
        unsigned int key = ((r & 127u) << 4) | src_chunk(r >> 7);
        atomicAdd(&hist[key], 1);
    }
    __syncthreads();

    // in-place exclusive scan of hist[2048]
    int base8 = t * 8;
    int v[8], lsum = 0;
#pragma unroll
    for (int j = 0; j < 8; j++) { v[j] = hist[base8 + j]; lsum += v[j]; }
    partial[t] = lsum;
    __syncthreads();
    for (int off = 1; off < 256; off <<= 1) {
        int x = (t >= off) ? partial[t - off] : 0;
        __syncthreads();
        partial[t] += x;
        __syncthreads();
    }
    int run = partial[t] - lsum;
#pragma unroll
    for (int j = 0; j < 8; j++) { hist[base8 + j] = run; run += v[j]; }
    __syncthreads();

    if (t < NPB) {
        int node = b * NPB + t;
        if (node < N_NODES) {
            int start = hist[t << 4];
            int end = (t < NPB - 1) ? hist[(t + 1) << 4] : cnt;
            rowse[node] = make_int2(base + start, base + end);
            dinv[node] = rsqrtf((float)(end - start + 1));   // +1 self-loop
        }
    }
    __syncthreads();

    for (int i = t; i < cnt; i += 256) {
        unsigned int r = recL[i];
        unsigned int key = ((r & 127u) << 4) | src_chunk(r >> 7);
        int pos = atomicAdd(&hist[key], 1);
        colL[pos] = (int)(r >> 7);
    }
    __syncthreads();
    for (int i = t; i < cnt; i += 256) colv[base + i] = colL[i];
}

// ---------------- MFMA GEMM (M x 128 @ 128 x N), fused BN-final+BN-apply+ReLU, dinv prescale ----------------

template <int ABF16, int MODE, int NT, int OBF16>
__global__ __launch_bounds__(256) void gemm_k(
    const void* __restrict__ Ap, const unsigned short* __restrict__ Wt,
    const float* __restrict__ bnSum, const float* __restrict__ bnSq,
    const float* __restrict__ gam, const float* __restrict__ bet,
    const float* __restrict__ dinv, void* __restrict__ Outp,
    int ncols, int ostride)
{
    __shared__ unsigned short WtL[NT * 16][136];
    __shared__ float sS[128], sT[128];

    int t = threadIdx.x;
    if (MODE) {
        if (t < 128) {
            float mean = bnSum[t] * (1.0f / N_NODES);
            float var = bnSq[t] * (1.0f / N_NODES) - mean * mean;
            float inv = rsqrtf(var + 1e-5f);
            float s = gam[t] * inv;
            sS[t] = s;
            sT[t] = bet[t] - mean * s;
        }
    }

    const int TOT = NT * 16 * 128;
    for (int e = t * 8; e < TOT; e += 256 * 8) {
        int n = e >> 7, k = e & 127;
        uint4 v = *(const uint4*)(Wt + e);
        *(uint4*)&WtL[n][k] = v;
    }
    __syncthreads();

    int wave = t >> 6, lane = t & 63;
    int quad = lane >> 4, m16 = lane & 15;
    int rbase = blockIdx.x * 128 + wave * 32;

    f32x4 acc[2][NT];
#pragma unroll
    for (int rt = 0; rt < 2; rt++)
#pragma unroll
        for (int ct = 0; ct < NT; ct++) acc[rt][ct] = (f32x4){0.f, 0.f, 0.f, 0.f};

#pragma unroll
    for (int kc = 0; kc < 4; kc++) {
        int kb = kc * 32 + quad * 8;
        bf16x8 afrag[2];
#pragma unroll
        for (int rt = 0; rt < 2; rt++) {
            int row = rbase + rt * 16 + m16;
            bool rv = (row < N_NODES);
            if (ABF16) {
                uint4 v = make_uint4(0, 0, 0, 0);
                if (rv) v = *(const uint4*)((const unsigned short*)Ap + (size_t)row * 128 + kb);
                if (MODE) {
                    unsigned int uu[4] = {v.x, v.y, v.z, v.w};
                    unsigned short* fp = (unsigned short*)&afrag[rt];
#pragma unroll
                    for (int i = 0; i < 4; i++) {
                        int k0 = kb + 2 * i;
                        float lo = fmaxf(bf_lo(uu[i]) * sS[k0] + sT[k0], 0.f);
                        float hi = fmaxf(bf_hi(uu[i]) * sS[k0 + 1] + sT[k0 + 1], 0.f);
                        fp[2 * i] = f2bf(lo);
                        fp[2 * i + 1] = f2bf(hi);
                    }
                } else {
                    afrag[rt] = *(bf16x8*)&v;
                }
            } else {
                const float* ap = (const float*)Ap + (size_t)row * 128 + kb;
                float4 f0 = make_float4(0.f, 0.f, 0.f, 0.f), f1 = f0;
                if (rv) { f0 = *(const float4*)ap; f1 = *(const float4*)(ap + 4); }
                unsigned short* fp = (unsigned short*)&afrag[rt];
                fp[0] = f2bf(f0.x); fp[1] = f2bf(f0.y); fp[2] = f2bf(f0.z); fp[3] = f2bf(f0.w);
                fp[4] = f2bf(f1.x); fp[5] = f2bf(f1.y); fp[6] = f2bf(f1.z); fp[7] = f2bf(f1.w);
            }
        }
#pragma unroll
        for (int ct = 0; ct < NT; ct++) {
            bf16x8 bfrag = *(bf16x8*)&WtL[ct * 16 + m16][kb];
#pragma unroll
            for (int rt = 0; rt < 2; rt++)
                acc[rt][ct] = __builtin_amdgcn_mfma_f32_16x16x32_bf16(
                    afrag[rt], bfrag, acc[rt][ct], 0, 0, 0);
        }
    }

#pragma unroll
    for (int rt = 0; rt < 2; rt++)
#pragma unroll
        for (int r = 0; r < 4; r++) {
            int row = rbase + rt * 16 + quad * 4 + r;
            if (row < N_NODES) {
                float d = dinv[row];
#pragma unroll
                for (int ct = 0; ct < NT; ct++) {
                    int c = ct * 16 + m16;
                    if (c < ncols) {
                        float val = acc[rt][ct][r] * d;
                        if (OBF16)
                            ((unsigned short*)Outp)[(size_t)row * ostride + c] = f2bf(val);
                        else
                            ((float*)Outp)[(size_t)row * ostride + c] = val;
                    }
                }
            }
        }
}

// ---------------- Aggregation: quarter-wave per node, 8 gathers in flight, fused BN stats ----------------
// Wave = 4 nodes (one per 16-lane quarter). Each quarter walks its node's CSR record list
// with full-row uint4 gathers. No cross-quarter reduction for the output (each quarter owns
// its node). Epilogue fuses self-loop + bias + dinv scale + bf16 store + BN sum/sq stats
// (quarter shfl_xor reduce -> 16 KB LDS block reduce -> 256 global atomics/block).

__global__ __launch_bounds__(1024) void agg4_k(
    const unsigned int* __restrict__ H, const int2* __restrict__ rowse,
    const int* __restrict__ colv, const float* __restrict__ dinv,
    const float* __restrict__ bias,
    float* __restrict__ bnSum, float* __restrict__ bnSq,
    unsigned int* __restrict__ out)
{
    __shared__ float red[2][16][16][8];      // 16 KB: [sum|sq][wave][c][k]

    int t = threadIdx.x;
    int w = t >> 6, lane = t & 63;
    int q = lane >> 4, c = lane & 15;
    int qb = q << 4;
    int node = blockIdx.x * 64 + w * 4 + q;
    bool valid = node < N_NODES;

    const uint4* H4 = (const uint4*)H;       // row = 16 uint4 (256 B)

    float a0 = 0.f, a1 = 0.f, a2 = 0.f, a3 = 0.f;
    float a4 = 0.f, a5 = 0.f, a6 = 0.f, a7 = 0.f;
    int rp = 0, re = 0;
    float dv = 0.f;
    if (valid) {
        int2 se = rowse[node];
        rp = se.x; re = se.y;
        dv = dinv[node];
        uint4 u = H4[(size_t)node * 16 + c];   // self-loop (prescaled row)
        a0 = bf_lo(u.x); a1 = bf_hi(u.x); a2 = bf_lo(u.y); a3 = bf_hi(u.y);
        a4 = bf_lo(u.z); a5 = bf_hi(u.z); a6 = bf_lo(u.w); a7 = bf_hi(u.w);
    }

    for (int j0 = rp; j0 < re; j0 += 16) {
        int m = min(16, re - j0);
        int idx = (c < m) ? colv[j0 + c] : 0;
        int tt = 0;
        for (; tt + 8 <= m; tt += 8) {       // 8 independent full-row gathers in flight
            int s0 = __shfl(idx, qb + tt + 0);
            int s1 = __shfl(idx, qb + tt + 1);
            int s2 = __shfl(idx, qb + tt + 2);
            int s3 = __shfl(idx, qb + tt + 3);
            int s4 = __shfl(idx, qb + tt + 4);
            int s5 = __shfl(idx, qb + tt + 5);
            int s6 = __shfl(idx, qb + tt + 6);
            int s7 = __shfl(idx, qb + tt + 7);
            uint4 u0 = H4[(size_t)s0 * 16 + c];
            uint4 u1 = H4[(size_t)s1 * 16 + c];
            uint4 u2 = H4[(size_t)s2 * 16 + c];
            uint4 u3 = H4[(size_t)s3 * 16 + c];
            uint4 u4 = H4[(size_t)s4 * 16 + c];
            uint4 u5 = H4[(size_t)s5 * 16 + c];
            uint4 u6 = H4[(size_t)s6 * 16 + c];
            uint4 u7 = H4[(size_t)s7 * 16 + c];
            a0 += (bf_lo(u0.x) + bf_lo(u1.x)) + (bf_lo(u2.x) + bf_lo(u3.x))
                + (bf_lo(u4.x) + bf_lo(u5.x)) + (bf_lo(u6.x) + bf_lo(u7.x));
            a1 += (bf_hi(u0.x) + bf_hi(u1.x)) + (bf_hi(u2.x) + bf_hi(u3.x))
                + (bf_hi(u4.x) + bf_hi(u5.x)) + (bf_hi(u6.x) + bf_hi(u7.x));
            a2 += (bf_lo(u0.y) + bf_lo(u1.y)) + (bf_lo(u2.y) + bf_lo(u3.y))
                + (bf_lo(u4.y) + bf_lo(u5.y)) + (bf_lo(u6.y) + bf_lo(u7.y));
            a3 += (bf_hi(u0.y) + bf_hi(u1.y)) + (bf_hi(u2.y) + bf_hi(u3.y))
                + (bf_hi(u4.y) + bf_hi(u5.y)) + (bf_hi(u6.y) + bf_hi(u7.y));
            a4 += (bf_lo(u0.z) + bf_lo(u1.z)) + (bf_lo(u2.z) + bf_lo(u3.z))
                + (bf_lo(u4.z) + bf_lo(u5.z)) + (bf_lo(u6.z) + bf_lo(u7.z));
            a5 += (bf_hi(u0.z) + bf_hi(u1.z)) + (bf_hi(u2.z) + bf_hi(u3.z))
                + (bf_hi(u4.z) + bf_hi(u5.z)) + (bf_hi(u6.z) + bf_hi(u7.z));
            a6 += (bf_lo(u0.w) + bf_lo(u1.w)) + (bf_lo(u2.w) + bf_lo(u3.w))
                + (bf_lo(u4.w) + bf_lo(u5.w)) + (bf_lo(u6.w) + bf_lo(u7.w));
            a7 += (bf_hi(u0.w) + bf_hi(u1.w)) + (bf_hi(u2.w) + bf_hi(u3.w))
                + (bf_hi(u4.w) + bf_hi(u5.w)) + (bf_hi(u6.w) + bf_hi(u7.w));
        }
        for (; tt + 4 <= m; tt += 4) {
            int s0 = __shfl(idx, qb + tt + 0);
            int s1 = __shfl(idx, qb + tt + 1);
            int s2 = __shfl(idx, qb + tt + 2);
            int s3 = __shfl(idx, qb + tt + 3);
            uint4 u0 = H4[(size_t)s0 * 16 + c];
            uint4 u1 = H4[(size_t)s1 * 16 + c];
            uint4 u2 = H4[(size_t)s2 * 16 + c];
            uint4 u3 = H4[(size_t)s3 * 16 + c];
            a0 += (bf_lo(u0.x) + bf_lo(u1.x)) + (bf_lo(u2.x) + bf_lo(u3.x));
            a1 += (bf_hi(u0.x) + bf_hi(u1.x)) + (bf_hi(u2.x) + bf_hi(u3.x));
            a2 += (bf_lo(u0.y) + bf_lo(u1.y)) + (bf_lo(u2.y) + bf_lo(u3.y));
            a3 += (bf_hi(u0.y) + bf_hi(u1.y)) + (bf_hi(u2.y) + bf_hi(u3.y));
            a4 += (bf_lo(u0.z) + bf_lo(u1.z)) + (bf_lo(u2.z) + bf_lo(u3.z));
            a5 += (bf_hi(u0.z) + bf_hi(u1.z)) + (bf_hi(u2.z) + bf_hi(u3.z));
            a6 += (bf_lo(u0.w) + bf_lo(u1.w)) + (bf_lo(u2.w) + bf_lo(u3.w));
            a7 += (bf_hi(u0.w) + bf_hi(u1.w)) + (bf_hi(u2.w) + bf_hi(u3.w));
        }
        for (; tt < m; tt++) {
            int s0 = __shfl(idx, qb + tt);
            uint4 u0 = H4[(size_t)s0 * 16 + c];
            a0 += bf_lo(u0.x); a1 += bf_hi(u0.x);
            a2 += bf_lo(u0.y); a3 += bf_hi(u0.y);
            a4 += bf_lo(u0.z); a5 += bf_hi(u0.z);
            a6 += bf_lo(u0.w); a7 += bf_hi(u0.w);
        }
    }

    // epilogue: lane owns channels 8c..8c+7 of its quarter's node
    float4 ba = ((const float4*)bias)[2 * c];
    float4 bb = ((const float4*)bias)[2 * c + 1];
    float v0 = a0 * dv + ba.x, v1 = a1 * dv + ba.y;
    float v2 = a2 * dv + ba.z, v3 = a3 * dv + ba.w;
    float v4 = a4 * dv + bb.x, v5 = a5 * dv + bb.y;
    float v6 = a6 * dv + bb.z, v7 = a7 * dv + bb.w;
    if (valid) {
        uint4 r;
        r.x = (unsigned int)f2bf(v0) | ((unsigned int)f2bf(v1) << 16);
        r.y = (unsigned int)f2bf(v2) | ((unsigned int)f2bf(v3) << 16);
        r.z = (unsigned int)f2bf(v4) | ((unsigned int)f2bf(v5) << 16);
        r.w = (unsigned int)f2bf(v6) | ((unsigned int)f2bf(v7) << 16);
        ((uint4*)out)[(size_t)node * 16 + c] = r;
    }

    // BN stats
    float sv[8], qv[8];
    float vv[8] = {v0, v1, v2, v3, v4, v5, v6, v7};
#pragma unroll
    for (int k = 0; k < 8; k++) {
        float x = valid ? vv[k] : 0.f;
        sv[k] = x; qv[k] = x * x;
    }
#pragma unroll
    for (int k = 0; k < 8; k++) {
        sv[k] += __shfl_xor(sv[k], 16); sv[k] += __shfl_xor(sv[k], 32);
        qv[k] += __shfl_xor(qv[k], 16); qv[k] += __shfl_xor(qv[k], 32);
    }
    if (q == 0) {
#pragma unroll
        for (int k = 0; k < 8; k++) {
            red[0][w][c][k] = sv[k];
            red[1][w][c][k] = qv[k];
        }
    }
    __syncthreads();
    if (t < 256) {
        int part = t >> 7, ch = t & 127;
        int cc = ch >> 3, k = ch & 7;
        float tot = 0.f;
#pragma unroll
        for (int ww = 0; ww < 16; ww++) tot += red[part][ww][cc][k];
        atomicAdd((part ? bnSq : bnSum) + ch, tot);
    }
}

// ---------------- Final aggregation (bf16 48-stride rows), quarter-wave + log_softmax ----------------

__global__ __launch_bounds__(256) void agg_out_k(
    const unsigned int* __restrict__ H, const int2* __restrict__ rowse,
    const int* __restrict__ colv, const float* __restrict__ dinv,
    const float* __restrict__ b2, float* __restrict__ out)
{
    int gw = (blockIdx.x * 256 + threadIdx.x) >> 6;
    int lane = threadIdx.x & 63;
    if (gw >= N_NODES) return;
    int q = lane >> 4;
    int c = lane & 15;
    bool ld = c < 12;              // 12 uint2 = 48 bf16 per row
    int2 se = rowse[gw];
    int rp = se.x, re = se.y;
    const uint2* H2 = (const uint2*)H;   // row = 12 uint2 (96 B)

    float a0 = 0.f, a1 = 0.f, a2 = 0.f, a3 = 0.f;
    if (q == 0 && ld) {
        uint2 u = H2[(size_t)gw * 12 + c];   // self (prescaled)
        a0 = bf_lo(u.x); a1 = bf_hi(u.x); a2 = bf_lo(u.y); a3 = bf_hi(u.y);
    }

    for (int j0 = rp; j0 < re; j0 += 64) {
        int idx = (j0 + lane < re) ? colv[j0 + lane] : 0;
        int n = min(64, re - j0);
        int nq = n >> 2;
        int t4 = 0;
        for (; t4 + 1 < nq; t4 += 2) {
            int sa = __shfl(idx, 4 * t4 + q);
            int sb = __shfl(idx, 4 * t4 + 4 + q);
            if (ld) {
                uint2 ua = H2[(size_t)sa * 12 + c];
                uint2 ub = H2[(size_t)sb * 12 + c];
                a0 += bf_lo(ua.x) + bf_lo(ub.x);
                a1 += bf_hi(ua.x) + bf_hi(ub.x);
                a2 += bf_lo(ua.y) + bf_lo(ub.y);
                a3 += bf_hi(ua.y) + bf_hi(ub.y);
            }
        }
        if (t4 < nq) {
            int sa = __shfl(idx, 4 * t4 + q);
            if (ld) {
                uint2 ua = H2[(size_t)sa * 12 + c];
                a0 += bf_lo(ua.x); a1 += bf_hi(ua.x);
                a2 += bf_lo(ua.y); a3 += bf_hi(ua.y);
            }
        }
        int rem = n & 3;
        if (rem) {
            int sa = __shfl(idx, (n - rem) + q);
            if (q < rem && ld) {
                uint2 ua = H2[(size_t)sa * 12 + c];
                a0 += bf_lo(ua.x); a1 += bf_hi(ua.x);
                a2 += bf_lo(ua.y); a3 += bf_hi(ua.y);
            }
        }
    }

    a0 += __shfl_xor(a0, 16); a0 += __shfl_xor(a0, 32);
    a1 += __shfl_xor(a1, 16); a1 += __shfl_xor(a1, 32);
    a2 += __shfl_xor(a2, 16); a2 += __shfl_xor(a2, 32);
    a3 += __shfl_xor(a3, 16); a3 += __shfl_xor(a3, 32);

    float d = dinv[gw];
    int ch = c * 4;
    float v0 = -INFINITY, v1 = -INFINITY, v2 = -INFINITY, v3 = -INFINITY;
    if (ld) {
        v0 = a0 * d + b2[ch];
        v1 = a1 * d + b2[ch + 1];
        v2 = a2 * d + b2[ch + 2];
        if (ch + 3 < OUTD) v3 = a3 * d + b2[ch + 3];
    }
    float m = fmaxf(fmaxf(v0, v1), fmaxf(v2, v3));
    m = fmaxf(m, __shfl_xor(m, 1));
    m = fmaxf(m, __shfl_xor(m, 2));
    m = fmaxf(m, __shfl_xor(m, 4));
    m = fmaxf(m, __shfl_xor(m, 8));
    float e = 0.f;
    if (ld) {
        e = __expf(v0 - m) + __expf(v1 - m) + __expf(v2 - m);
        if (ch + 3 < OUTD) e += __expf(v3 - m);
    }
    float sum = e;
    sum += __shfl_xor(sum, 1);
    sum += __shfl_xor(sum, 2);
    sum += __shfl_xor(sum, 4);
    sum += __shfl_xor(sum, 8);
    float ls = logf(sum);
    if (q == 0 && ld) {
        float* op = out + (size_t)gw * OUTD + ch;
        op[0] = v0 - m - ls;
        op[1] = v1 - m - ls;
        op[2] = v2 - m - ls;
        if (ch + 3 < OUTD) op[3] = v3 - m - ls;
    }
}

// ---------------- launch ----------------

extern "C" void kernel_launch(void* const* d_in, const int* in_sizes, int n_in,
                              void* d_out, int out_size, void* d_ws, size_t ws_size,
                              hipStream_t stream)
{
    const float* x   = (const float*)d_in[0];
    const int*   ei  = (const int*)d_in[1];
    const float* W0  = (const float*)d_in[2];
    const float* b0  = (const float*)d_in[3];
    const float* W1  = (const float*)d_in[4];
    const float* b1  = (const float*)d_in[5];
    const float* W2  = (const float*)d_in[6];
    const float* b2  = (const float*)d_in[7];
    const float* g0  = (const float*)d_in[8];
    const float* be0 = (const float*)d_in[9];
    const float* g1  = (const float*)d_in[10];
    const float* be1 = (const float*)d_in[11];
    const int* srcv = ei;
    const int* dstv = ei + N_EDGES;

    char* w = (char*)d_ws;
    unsigned int* H0 = (unsigned int*)w;  w += (size_t)N_NODES * 128 * 2;   // bf16 [N][128]
    unsigned int* H1 = (unsigned int*)w;  w += (size_t)N_NODES * 128 * 2;   // bf16 [N][128]
    unsigned int* Hf = (unsigned int*)w;  w += (size_t)N_NODES * OSTR * 2;  // bf16 [N][48]
    unsigned int* binned = (unsigned int*)w; w += (size_t)NB * BCAP * 4;    // 8.0 MB
    int* colv = (int*)w;        w += (size_t)NB * BCAP * 4;                 // 8.0 MB (fixed regions)
    unsigned short* Wt0 = (unsigned short*)w; w += 16384 * 2;
    unsigned short* Wt1 = (unsigned short*)w; w += 16384 * 2;
    unsigned short* Wt2 = (unsigned short*)w; w += 48 * 128 * 2;
    int2* rowse = (int2*)w;     w += (size_t)N_NODES * 8;
    float* dinv = (float*)w;    w += (size_t)N_NODES * 4;
    // single-memset region: gcur (784 ints) + bnS0,bnQ0,bnS1,bnQ1 (512 floats)
    int* gcur = (int*)w;        w += 784 * 4;
    float* bnS0 = (float*)w;    w += 128 * 4;
    float* bnQ0 = (float*)w;    w += 128 * 4;
    float* bnS1 = (float*)w;    w += 128 * 4;
    float* bnQ1 = (float*)w;    w += 128 * 4;

    int gb = (N_NODES + 127) / 128;       // 782
    int ab = (N_NODES * 64 + 255) / 256;  // 25000

    hipMemsetAsync(gcur, 0, (784 + 512) * 4, stream);

    binA_k<<<NCHB + CWB, 256, 0, stream>>>(srcv, dstv, gcur, binned,
                                           W0, W1, W2, Wt0, Wt1, Wt2);
    binB_k<<<NB, 256, 0, stream>>>(binned, gcur, rowse, dinv, colv);

    // Layer 0: x fp32 -> H0 bf16 (dinv-prescaled); agg fuses bias + BN stats
    gemm_k<0, 0, 8, 1><<<gb, 256, 0, stream>>>(x, Wt0, nullptr, nullptr, nullptr, nullptr,
                                               dinv, H0, 128, 128);
    agg4_k<<<NAB, 1024, 0, stream>>>(H0, rowse, colv, dinv, b0, bnS0, bnQ0, H1);

    // Layer 1: BN-final+BN-apply+ReLU fused into gemm, bf16 MFMA
    gemm_k<1, 1, 8, 1><<<gb, 256, 0, stream>>>(H1, Wt1, bnS0, bnQ0, g0, be0,
                                               dinv, H0, 128, 128);
    agg4_k<<<NAB, 1024, 0, stream>>>(H0, rowse, colv, dinv, b1, bnS1, bnQ1, H1);

    // Layer 2: 47-wide out (bf16, stride 48) + fused log_softmax aggregation
    gemm_k<1, 1, 3, 1><<<gb, 256, 0, stream>>>(H1, Wt2, bnS1, bnQ1, g1, be1,
                                               dinv, Hf, OUTD, OSTR);
    agg_out_k<<<ab, 256, 0, stream>>>(Hf, rowse, colv, dinv, b2, (float*)d_out);
}